// Round 5
// baseline (227.636 us; speedup 1.0000x reference)
//
#include <hip/hip_runtime.h>
#include <math.h>

// Problem constants: B=128, C=48, H=W=64, p=32, N=4, D=49152
#define PLANE 4096            // 64*64
#define OUT0 25165824         // 128*48*64*64 (flat offset of logdet output)

typedef float fx4 __attribute__((ext_vector_type(4)));

// ws layout (floats):
#define WS_GW   0             // [2304]  Gw[rc*576 + k*12 + j] = G[rc*12+j][k]
#define WS_PART 4096          // [2048*4] per-block partial scores {s11,s12,s21,s22}

// ---------------- k0: Gw[rc][k][j] = G[rc*12+j][k] = sum_o Wq[o,r]*Wk[o,k] (3 pairs) --
__global__ void g_kernel(const float* __restrict__ Wq1, const float* __restrict__ Wq2,
                         const float* __restrict__ Wq3, const float* __restrict__ Wk1,
                         const float* __restrict__ Wk2, const float* __restrict__ Wk3,
                         float* __restrict__ Gw) {
    int idx = blockIdx.x * 256 + threadIdx.x;
    if (idx >= 2304) return;
    int rc = idx / 576, rem = idx % 576;
    int k = rem / 12, j = rem % 12;
    int r = rc * 12 + j;
    float acc = 0.f;
    for (int o = 0; o < 48; ++o) {
        acc = fmaf(Wq1[o * 48 + r], Wk1[o * 48 + k], acc);
        acc = fmaf(Wq2[o * 48 + r], Wk2[o * 48 + k], acc);
        acc = fmaf(Wq3[o * 48 + r], Wk3[o * 48 + k], acc);
    }
    Gw[idx] = acc;
}

// ---------------- k1: scores, wave-uniform r-chunk ----------
// grid 2048 = (b:128) x (s:2) x (g:8 row-groups); block 256 = 4 waves.
// Wave w owns r-chunk rc=w (rows rc*12..rc*12+11), lanes = 64 pixel-pairs.
// G read at wave-uniform addresses -> s_load (scalar pipe, no VALU/LDS cost).
// u{1,2}[j] += G[r_j,k] * v{1,2}[k]; own v-chunk captured in-stream (uniform branch).
__global__ __launch_bounds__(256, 4) void score_kernel(const float* __restrict__ x,
                                                       const float* __restrict__ Gw,
                                                       float* __restrict__ part) {
    int tid = threadIdx.x;
    int lane = tid & 63;
    int rc = __builtin_amdgcn_readfirstlane(tid >> 6);   // wave-uniform r-chunk 0..3
    int bid = blockIdx.x;
    int g = bid & 7;
    int s = (bid >> 3) & 1;
    int b = bid >> 4;
    int i = g * 4 + (lane >> 4);          // row in patch [0,32)
    int w = 32 * s + ((lane & 15) << 1) + s;

    const float* p1 = x + (size_t)b * (48 * PLANE) + i * 64 + w;   // top (n=s)
    const float* p2 = p1 + 32 * 64;                                 // bottom (n=s+2)
    const float* gw = Gw + rc * 576;                                // uniform -> s_load

    float u1[12], u2[12], a1[12], a2[12];
#pragma unroll
    for (int j = 0; j < 12; ++j) { u1[j] = 0.f; u2[j] = 0.f; a1[j] = 0.f; a2[j] = 0.f; }

    float tb[4], vb[4];
    tb[0] = p1[0];         vb[0] = p2[0];
    tb[1] = p1[PLANE];     vb[1] = p2[PLANE];
    tb[2] = p1[2 * PLANE]; vb[2] = p2[2 * PLANE];

#pragma unroll
    for (int k = 0; k < 48; ++k) {
        if (k + 3 < 48) {   // compile-time per unrolled iter
            tb[(k + 3) & 3] = p1[(k + 3) * PLANE];
            vb[(k + 3) & 3] = p2[(k + 3) * PLANE];
        }
        float t = tb[k & 3], v = vb[k & 3];
        const float* gk = gw + k * 12;    // 48B-aligned uniform row
#pragma unroll
        for (int j = 0; j < 12; ++j) {
            float gv = gk[j];
            u1[j] = fmaf(gv, t, u1[j]);
            u2[j] = fmaf(gv, v, u2[j]);
        }
        if (rc == k / 12) {               // wave-uniform branch (k/12 is a literal)
            a1[k % 12] = t;
            a2[k % 12] = v;
        }
    }

    float s11 = 0.f, s12 = 0.f, s21 = 0.f, s22 = 0.f;
#pragma unroll
    for (int j = 0; j < 12; ++j) {
        s11 = fmaf(a1[j], u1[j], s11);
        s12 = fmaf(a1[j], u2[j], s12);
        s21 = fmaf(a2[j], u1[j], s21);
        s22 = fmaf(a2[j], u2[j], s22);
    }

    // butterfly over 64 pixel-lanes
    for (int off = 1; off < 64; off <<= 1) {
        s11 += __shfl_xor(s11, off, 64);
        s12 += __shfl_xor(s12, off, 64);
        s21 += __shfl_xor(s21, off, 64);
        s22 += __shfl_xor(s22, off, 64);
    }
    __shared__ float red[4][4];
    int wid = tid >> 6;
    if (lane == 0) {
        red[wid][0] = s11; red[wid][1] = s12; red[wid][2] = s21; red[wid][3] = s22;
    }
    __syncthreads();
    if (tid < 4) {   // sum the 4 r-chunks; plain store (no atomics)
        part[bid * 4 + tid] = red[0][tid] + red[1][tid] + red[2][tid] + red[3][tid];
    }
}

// ---------------- k2: streaming output + fused attn/softmax/logdet ----------------
// Per (b,s) scores = sum of 8 g-block partials at part[(b*16+s*8+g)*4 + q].
__global__ __launch_bounds__(256) void out_kernel(const float* __restrict__ x,
                                                  const float* __restrict__ part,
                                                  const float* __restrict__ logdet_in,
                                                  const float* __restrict__ off_p,
                                                  const float* __restrict__ off2_p,
                                                  float* __restrict__ out,
                                                  float* __restrict__ out_logdet) {
    int bc = blockIdx.x;            // 128*48
    int b = bc / 48;

    const float inv_scale = 4.5105361e-3f;   // 1/sqrt(49152)
    float off = off_p[0];
    float c2o = off2_p[0];
    float ld = 0.f;
    float Ad[4], Ao[4];
#pragma unroll
    for (int s = 0; s < 2; ++s) {
        float sc[4] = {0.f, 0.f, 0.f, 0.f};
#pragma unroll
        for (int g = 0; g < 8; ++g) {
            const float* pp = part + ((b * 16) + s * 8 + g) * 4;
#pragma unroll
            for (int q = 0; q < 4; ++q) sc[q] += pp[q];
        }
        float stt = sc[0] * inv_scale;   // (top,top)
        float stb = sc[1] * inv_scale;   // (top,bot)
        float sbt = sc[2] * inv_scale;   // (bot,top)
        float sbb = sc[3] * inv_scale;   // (bot,bot)

        float m0 = fmaxf(fmaxf(stt, stb), 0.f);
        float e00 = expf(stt - m0), e01 = expf(stb - m0), ez0 = expf(-m0);
        float d0 = e00 + e01 + 2.f * ez0;
        float ptt = e00 / d0, ptb = e01 / d0;
        float m1 = fmaxf(fmaxf(sbt, sbb), 0.f);
        float e10 = expf(sbt - m1), e11 = expf(sbb - m1), ez1 = expf(-m1);
        float d1 = e10 + e11 + 2.f * ez1;
        float pbt = e10 / d1, pbb = e11 / d1;

        float adt = ptt + c2o + off;
        float aot = ptb + c2o;
        float adb = pbb + c2o + off;
        float aob = pbt + c2o;
        Ad[s] = adt; Ao[s] = aot; Ad[s + 2] = adb; Ao[s + 2] = aob;
        float det = adt * adb - aot * aob;
        ld += logf(fabsf(det));
    }
    if ((bc - b * 48) == 0 && threadIdx.x == 0) {
        out_logdet[b] = logdet_in[b] + ld * 24576.0f;
    }

    const fx4* xb4 = (const fx4*)(x + (size_t)bc * PLANE);
    fx4* ob4 = (fx4*)(out + (size_t)bc * PLANE);
    int tid = threadIdx.x;
#pragma unroll
    for (int it = 0; it < 2; ++it) {
        int f = it * 256 + tid;       // 0..511
        int h = f >> 4;               // 0..31
        int w4 = f & 15;
        fx4 xt = xb4[h * 16 + w4];
        fx4 xv = xb4[(h + 32) * 16 + w4];
        int wb = w4 >> 3;             // 0: w<32, 1: w>=32
        float Adt = wb ? Ad[1] : Ad[0];
        float Aot = wb ? Ao[1] : Ao[0];
        float Adb = wb ? Ad[3] : Ad[2];
        float Aob = wb ? Ao[3] : Ao[2];

        fx4 rt, rv;
#pragma unroll
        for (int q = 0; q < 4; ++q) {
            int e = (wb + q) & 1;     // w component parity
            float t = xt[q], v = xv[q];
            float mt = fmaf(Adt, t, Aot * v);
            float mv = fmaf(Adb, v, Aob * t);
            rt[q] = e ? mt : t;
            rv[q] = e ? mv : v;
        }
        __builtin_nontemporal_store(rt, &ob4[h * 16 + w4]);
        __builtin_nontemporal_store(rv, &ob4[(h + 32) * 16 + w4]);
    }
}

extern "C" void kernel_launch(void* const* d_in, const int* in_sizes, int n_in,
                              void* d_out, int out_size, void* d_ws, size_t ws_size,
                              hipStream_t stream) {
    const float* x      = (const float*)d_in[0];
    const float* logdet = (const float*)d_in[1];
    const float* Wq1    = (const float*)d_in[2];
    const float* Wq2    = (const float*)d_in[3];
    const float* Wq3    = (const float*)d_in[4];
    const float* Wk1    = (const float*)d_in[5];
    const float* Wk2    = (const float*)d_in[6];
    const float* Wk3    = (const float*)d_in[7];
    const float* off    = (const float*)d_in[8];
    const float* off2   = (const float*)d_in[9];
    // d_in[10] (offset3) is a uniform pre-softmax shift -> cancels; unused.

    float* out = (float*)d_out;
    float* ws  = (float*)d_ws;
    float* Gw   = ws + WS_GW;
    float* part = ws + WS_PART;

    g_kernel<<<9, 256, 0, stream>>>(Wq1, Wq2, Wq3, Wk1, Wk2, Wk3, Gw);
    score_kernel<<<2048, 256, 0, stream>>>(x, Gw, part);
    out_kernel<<<6144, 256, 0, stream>>>(x, part, logdet, off, off2, out, out + OUT0);
}